// Round 12
// baseline (193.529 us; speedup 1.0000x reference)
//
#include <hip/hip_runtime.h>
#include <stdint.h>

// LIF spike encoder — two-phase, bit-exact fp32.
//   Dense history: R6 154 (x-LDS + W-f4 stream, 16.8 MB/CU L1-bound) |
//   R10 ~125 (W reg-dbuf R=2, x scalar-path) | R11 ~120 (R=4, bytes halved,
//   NULL => not byte-bound; diagnosis: x s_load lgkmcnt stalls ~2000 cyc/iter,
//   SGPR budget forbids hoisting).
//   R12 (this): x in LDS (broadcast ds_read_b128, independent pipe, one-time
//   stage + one barrier) + W reg-dbuf float2 R=4 (4.2 MB/CU). n-fast grid
//   keeps per-XCD W slice 2 MB L2-resident (proven invariant).
// Bit-exactness: each output = ONE register, one fmaf per k, k=0..2047
// ascending — identical chain to all passing rounds. Sparse phase: ordered
// adds over sorted spike list == dense chain exactly.

#define BATCHSZ 256
#define NU      2048
#define TSTEPS  128
#define BLK     1024
#define NWAVES  (BLK / 64)

// ---------------- Phase A: dense GEMM (t=1), bit-exact chain ----------------
// block 128 thr (2 waves); BM=8 rows (4/wave) x BN=128 cols (2/lane).
#define D_BN 128
#define D_BM 8

__global__ __launch_bounds__(128) void lif_dense_v1(
    const float* __restrict__ x,
    const float* __restrict__ W,
    float* __restrict__ ws)
{
    __shared__ float s_x[D_BM * NU];        // 64 KB: the block's 8 x-rows

    const int tid  = threadIdx.x;
    const int lane = tid & 63;
    const int n0   = blockIdx.x * D_BN;     // n-tile FAST -> xcd = bid%8
    const int m0   = blockIdx.y * D_BM;

    // ---- stage 8 contiguous x rows (flat float4 copy, coalesced)
    {
        const float4* xg = (const float4*)(x + (size_t)m0 * NU);
        float4*       xs = (float4*)s_x;
        #pragma unroll
        for (int j = 0; j < 32; ++j)        // 4096 float4 / 128 threads
            xs[j * 128 + tid] = xg[j * 128 + tid];
    }
    __syncthreads();

    const int rb = (tid >> 6) * 4;          // wave row base: 0 or 4
    const float* xw = &s_x[rb * NU];        // this wave's 4 rows (LDS)

    const float* wp = W + n0 + lane * 2;    // this thread's 2 cols

    float2 bA[16], bB[16];                  // two 16-deep W prefetch banks
    float2 acc[4];
    #pragma unroll
    for (int r = 0; r < 4; ++r) { acc[r].x = 0.0f; acc[r].y = 0.0f; }

    #pragma unroll
    for (int j = 0; j < 16; ++j)            // preload k = 0..15
        bA[j] = *(const float2*)(wp + (size_t)j * NU);

    for (int k0 = 0; k0 < NU; k0 += 32) {
        // prefetch k0+16..k0+31 into bB (always in range)
        #pragma unroll
        for (int j = 0; j < 16; ++j)
            bB[j] = *(const float2*)(wp + (size_t)(k0 + 16 + j) * NU);

        // compute k0..k0+15 from bA (k ascending; q = 4 k per step)
        #pragma unroll
        for (int q = 0; q < 4; ++q) {
            float4 xq[4];                   // ds_read_b128: 4 rows x 4 k
            #pragma unroll
            for (int r = 0; r < 4; ++r)     // broadcast (uniform addr)
                xq[r] = *(const float4*)&xw[r * NU + k0 + q * 4];
            const float* xf = (const float*)&xq[0];
            #pragma unroll
            for (int kk = 0; kk < 4; ++kk) {
                float2 wv = bA[q * 4 + kk];
                #pragma unroll
                for (int r = 0; r < 4; ++r) {
                    float xv = xf[r * 4 + kk];
                    acc[r].x = __builtin_fmaf(xv, wv.x, acc[r].x);
                    acc[r].y = __builtin_fmaf(xv, wv.y, acc[r].y);
                }
            }
        }

        // prefetch k0+32..k0+47 into bA
        if (k0 + 32 < NU) {
            #pragma unroll
            for (int j = 0; j < 16; ++j)
                bA[j] = *(const float2*)(wp + (size_t)(k0 + 32 + j) * NU);
        }

        // compute k0+16..k0+31 from bB
        #pragma unroll
        for (int q = 0; q < 4; ++q) {
            float4 xq[4];
            #pragma unroll
            for (int r = 0; r < 4; ++r)
                xq[r] = *(const float4*)&xw[r * NU + k0 + 16 + q * 4];
            const float* xf = (const float*)&xq[0];
            #pragma unroll
            for (int kk = 0; kk < 4; ++kk) {
                float2 wv = bB[q * 4 + kk];
                #pragma unroll
                for (int r = 0; r < 4; ++r) {
                    float xv = xf[r * 4 + kk];
                    acc[r].x = __builtin_fmaf(xv, wv.x, acc[r].x);
                    acc[r].y = __builtin_fmaf(xv, wv.y, acc[r].y);
                }
            }
        }
    }

    #pragma unroll
    for (int r = 0; r < 4; ++r)
        *(float2*)&ws[(size_t)(m0 + rb + r) * NU + n0 + lane * 2] = acc[r];
}

// ---------------- Phase B: recurrence from t=2 (unchanged, proven) ---------
__global__ __launch_bounds__(BLK) void lif_recurrence(
    const float* __restrict__ x,
    const float* __restrict__ W,
    const float* __restrict__ V1,
    float* __restrict__ out)
{
    const int b    = blockIdx.x;
    const int tid  = threadIdx.x;
    const int lane = tid & 63;
    const int wid  = tid >> 6;

    __shared__ int           s_idx[NU];      // spiking row offsets (k*NU)
    __shared__ unsigned char s_flag[NU];
    __shared__ int           s_wsum[NWAVES];
    __shared__ int           s_cnt;

    const int n0 = tid;
    const int n1 = tid + BLK;

    float* outb = out + (size_t)b * TSTEPS * NU;   // (B, T, N)

    float V0, V1r;
    int   z0, z1;
    {
        float x0 = x[(size_t)b * NU + n0];
        float x1 = x[(size_t)b * NU + n1];
        outb[n0] = x0;
        outb[n1] = x1;
        V0  = V1[(size_t)b * NU + n0];
        V1r = V1[(size_t)b * NU + n1];
        z0 = V0  > 1.0f;
        z1 = V1r > 1.0f;
        float* f1 = outb + NU;
        f1[n0] = z0 ? 1.0f : 0.0f;
        f1[n1] = z1 ? 1.0f : 0.0f;
        s_flag[n0] = (unsigned char)z0;
        s_flag[n1] = (unsigned char)z1;
    }
    __syncthreads();

    for (int t = 2; t < TSTEPS; ++t) {
        int f0 = s_flag[2 * tid];
        int f1 = s_flag[2 * tid + 1];
        int c  = f0 + f1;
        int v  = c;
        #pragma unroll
        for (int d = 1; d < 64; d <<= 1) {
            int o = __shfl_up(v, d);
            if (lane >= d) v += o;
        }
        if (lane == 63) s_wsum[wid] = v;
        __syncthreads();
        int base = 0;
        #pragma unroll
        for (int w = 0; w < NWAVES; ++w) base += (w < wid) ? s_wsum[w] : 0;
        int off = base + v - c;                   // exclusive prefix
        if (f0) s_idx[off++] = (2 * tid) * NU;
        if (f1) s_idx[off]   = (2 * tid + 1) * NU;
        if (tid == BLK - 1) s_cnt = base + v;
        __syncthreads();

        int cnt = s_cnt;
        if (cnt == 0) {
            size_t  elems  = (size_t)(TSTEPS - t) * NU;
            float4* p      = (float4*)(outb + (size_t)t * NU);
            int     chunks = (int)(elems / 4);
            float4  zz; zz.x = zz.y = zz.z = zz.w = 0.0f;
            for (int i = tid; i < chunks; i += BLK) p[i] = zz;
            return;
        }

        float I0 = 0.0f, I1 = 0.0f;
        const float* Wc = W + tid;
        int i = 0;
        for (; i + 4 <= cnt; i += 4) {
            const float* r0 = Wc + s_idx[i];
            const float* r1 = Wc + s_idx[i + 1];
            const float* r2 = Wc + s_idx[i + 2];
            const float* r3 = Wc + s_idx[i + 3];
            float a0 = r0[0], b0 = r0[BLK];
            float a1 = r1[0], b1 = r1[BLK];
            float a2 = r2[0], b2 = r2[BLK];
            float a3 = r3[0], b3 = r3[BLK];
            I0 += a0; I0 += a1; I0 += a2; I0 += a3;   // order preserved
            I1 += b0; I1 += b1; I1 += b2; I1 += b3;
        }
        for (; i < cnt; ++i) {
            const float* r = Wc + s_idx[i];
            I0 += r[0];
            I1 += r[BLK];
        }

        float d0 = 0.90483741803595952f * V0;     // one rounding
        float d1 = 0.90483741803595952f * V1r;
        asm volatile("" : "+v"(d0), "+v"(d1));    // forbid fma-contraction
        float nv0 = (z0 ? 0.0f : d0) + I0;        // one rounding
        float nv1 = (z1 ? 0.0f : d1) + I1;
        V0 = nv0; V1r = nv1;
        z0 = nv0 > 1.0f;
        z1 = nv1 > 1.0f;

        float* po = outb + (size_t)t * NU;
        po[n0] = z0 ? 1.0f : 0.0f;
        po[n1] = z1 ? 1.0f : 0.0f;
        s_flag[n0] = (unsigned char)z0;
        s_flag[n1] = (unsigned char)z1;
        __syncthreads();
    }
}

// ---------------- Fallback: round-4 fused kernel (proven) ------------------
__global__ __launch_bounds__(BLK) void lif_fused(
    const float* __restrict__ x,
    const float* __restrict__ W,
    float* __restrict__ out)
{
    const int b    = blockIdx.x;
    const int tid  = threadIdx.x;
    const int lane = tid & 63;
    const int wid  = tid >> 6;

    __shared__ float         s_x[NU];
    __shared__ int           s_idx[NU];
    __shared__ unsigned char s_flag[NU];
    __shared__ int           s_wsum[NWAVES];
    __shared__ int           s_cnt;

    const int n0 = tid;
    const int n1 = tid + BLK;
    float* outb = out + (size_t)b * TSTEPS * NU;

    {
        float x0 = x[(size_t)b * NU + n0];
        float x1 = x[(size_t)b * NU + n1];
        s_x[n0] = x0; s_x[n1] = x1;
        outb[n0] = x0; outb[n1] = x1;
    }
    __syncthreads();

    float I0 = 0.0f, I1 = 0.0f;
    {
        const float* Wc = W + tid;
        #pragma unroll 8
        for (int k = 0; k < NU; ++k) {
            float xk = s_x[k];
            const float* wr = Wc + (size_t)k * NU;
            I0 = __builtin_fmaf(xk, wr[0],   I0);
            I1 = __builtin_fmaf(xk, wr[BLK], I1);
        }
    }

    float V0 = 0.0f, V1 = 0.0f;
    int   z0 = 0,    z1 = 0;

    for (int t = 1; t < TSTEPS; ++t) {
        if (t >= 2) {
            int f0 = s_flag[2 * tid];
            int f1 = s_flag[2 * tid + 1];
            int c  = f0 + f1;
            int v  = c;
            #pragma unroll
            for (int d = 1; d < 64; d <<= 1) {
                int o = __shfl_up(v, d);
                if (lane >= d) v += o;
            }
            if (lane == 63) s_wsum[wid] = v;
            __syncthreads();
            int base = 0;
            #pragma unroll
            for (int w = 0; w < NWAVES; ++w) base += (w < wid) ? s_wsum[w] : 0;
            int off = base + v - c;
            if (f0) s_idx[off++] = 2 * tid;
            if (f1) s_idx[off]   = 2 * tid + 1;
            if (tid == BLK - 1) s_cnt = base + v;
            __syncthreads();

            int cnt = s_cnt;
            if (cnt == 0) {
                size_t  elems  = (size_t)(TSTEPS - t) * NU;
                float4* p      = (float4*)(outb + (size_t)t * NU);
                int     chunks = (int)(elems / 4);
                float4  zz; zz.x = zz.y = zz.z = zz.w = 0.0f;
                for (int i = tid; i < chunks; i += BLK) p[i] = zz;
                return;
            }

            I0 = 0.0f; I1 = 0.0f;
            const float* Wc = W + tid;
            int i = 0;
            for (; i + 2 <= cnt; i += 2) {
                const float* r0 = Wc + (size_t)s_idx[i]     * NU;
                const float* r1 = Wc + (size_t)s_idx[i + 1] * NU;
                float a0 = r0[0], b0 = r0[BLK];
                float a1 = r1[0], b1 = r1[BLK];
                I0 += a0; I0 += a1;
                I1 += b0; I1 += b1;
            }
            for (; i < cnt; ++i) {
                const float* r = Wc + (size_t)s_idx[i] * NU;
                I0 += r[0];
                I1 += r[BLK];
            }
        }

        float d0 = 0.90483741803595952f * V0;
        float d1 = 0.90483741803595952f * V1;
        asm volatile("" : "+v"(d0), "+v"(d1));
        float nv0 = (z0 ? 0.0f : d0) + I0;
        float nv1 = (z1 ? 0.0f : d1) + I1;
        V0 = nv0; V1 = nv1;
        z0 = nv0 > 1.0f;
        z1 = nv1 > 1.0f;

        float* po = outb + (size_t)t * NU;
        po[n0] = z0 ? 1.0f : 0.0f;
        po[n1] = z1 ? 1.0f : 0.0f;
        s_flag[n0] = (unsigned char)z0;
        s_flag[n1] = (unsigned char)z1;
        __syncthreads();
    }
}

extern "C" void kernel_launch(void* const* d_in, const int* in_sizes, int n_in,
                              void* d_out, int out_size, void* d_ws, size_t ws_size,
                              hipStream_t stream) {
    const float* x = (const float*)d_in[0];   // (256, 2048) fp32
    const float* W = (const float*)d_in[1];   // (2048, 2048) fp32
    if (n_in >= 2 && in_sizes[0] == NU * NU && in_sizes[1] == BATCHSZ * NU) {
        const float* t = x; x = W; W = t;     // defensive input-order swap
    }
    float* out = (float*)d_out;               // (B, T, N) fp32

    const size_t need = (size_t)BATCHSZ * NU * sizeof(float);   // 2 MB
    if (ws_size >= need) {
        float* V1 = (float*)d_ws;
        hipLaunchKernelGGL(lif_dense_v1,
                           dim3(NU / D_BN, BATCHSZ / D_BM), dim3(128), 0, stream,
                           x, W, V1);
        hipLaunchKernelGGL(lif_recurrence,
                           dim3(BATCHSZ), dim3(BLK), 0, stream,
                           x, W, V1, out);
    } else {
        hipLaunchKernelGGL(lif_fused, dim3(BATCHSZ), dim3(BLK), 0, stream,
                           x, W, out);
    }
}

// Round 13
// 168.417 us; speedup vs baseline: 1.1491x; 1.1491x over previous
//
#include <hip/hip_runtime.h>
#include <stdint.h>

// LIF spike encoder — two-phase, bit-exact fp32.
//   Dense diagnosis (R10-R12 nulls on the x-path): dense is L2-SERVICE bound
//   at the XCD level (~450 B/cyc/XCD; measured 134 MB/XCD in 125 us). The 16
//   W loads of a half take ~2300 cyc to drain the per-XCD L2 queue fed by 128
//   waves x 8 lines each. Lever: L1 dedup — make all 4 waves/CU read the SAME
//   W lines concurrently.
//   R13 (this): swizzled grid (xcd = bid&7 keeps the 2 MB/XCD W slice; within
//   an XCD, 32 consecutive blocks share ONE 128-col slice so CU-paired blocks
//   stream identical W lines -> L1 dedup up to 4x). Both W and x are
//   register-double-banked (x prefetched from LDS one 16-k half ahead):
//   compute phase has zero load-use waits.
// Bit-exactness: each output = ONE register, one fmaf per k, k=0..2047
// ascending — identical chain to all passing rounds. Sparse phase: ordered
// adds over sorted spike list == dense chain exactly.

#define BATCHSZ 256
#define NU      2048
#define TSTEPS  128
#define BLK     1024
#define NWAVES  (BLK / 64)

// ---------------- Phase A: dense GEMM (t=1), bit-exact chain ----------------
// 512 blocks x 128 thr; BM=8 (4 rows/wave) x BN=128 (2 cols/lane, float2).
#define D_BN 128
#define D_BM 8

__global__ __launch_bounds__(128) void lif_dense_v1(
    const float* __restrict__ x,
    const float* __restrict__ W,
    float* __restrict__ ws)
{
    __shared__ float s_x[D_BM * NU];        // 64 KB: the block's 8 x-rows

    const int tid  = threadIdx.x;
    const int lane = tid & 63;

    // swizzle: keep xcd = bid&7 (XCD-local 2 MB W slice) AND give the 32
    // consecutive blocks of each XCD the same n-slice (CU L1 dedup).
    const int bid    = blockIdx.x;
    const int xcd    = bid & 7;
    const int w      = bid >> 3;            // 0..63 within XCD
    const int n_tile = xcd * 2 + (w >> 5);  // 0..15
    const int m_tile = w & 31;              // 0..31
    const int n0     = n_tile * D_BN;
    const int m0     = m_tile * D_BM;

    // ---- stage 8 contiguous x rows (flat float4 copy, coalesced)
    {
        const float4* xg = (const float4*)(x + (size_t)m0 * NU);
        float4*       xs = (float4*)s_x;
        #pragma unroll
        for (int j = 0; j < 32; ++j)        // 4096 float4 / 128 threads
            xs[j * 128 + tid] = xg[j * 128 + tid];
    }
    __syncthreads();

    const int rb = (tid >> 6) * 4;          // wave row base: 0 or 4
    const float* xw = &s_x[rb * NU];        // this wave's 4 rows (LDS)
    const float* wp = W + n0 + lane * 2;    // this thread's 2 cols

    float2 wA[16], wB[16];                  // W banks (16 k each)
    float4 xA[16], xB[16];                  // x banks: [q*4+r] = rows r, 4 k
    float2 acc[4];
    #pragma unroll
    for (int r = 0; r < 4; ++r) { acc[r].x = 0.0f; acc[r].y = 0.0f; }

    // prologue: load half 0 into A banks
    #pragma unroll
    for (int j = 0; j < 16; ++j)
        wA[j] = *(const float2*)(wp + (size_t)j * NU);
    #pragma unroll
    for (int q = 0; q < 4; ++q)
        #pragma unroll
        for (int r = 0; r < 4; ++r)
            xA[q * 4 + r] = *(const float4*)&xw[r * NU + q * 4];

    for (int k0 = 0; k0 < NU; k0 += 32) {
        // ---- prefetch half (k0+16) into B banks
        #pragma unroll
        for (int j = 0; j < 16; ++j)
            wB[j] = *(const float2*)(wp + (size_t)(k0 + 16 + j) * NU);
        #pragma unroll
        for (int q = 0; q < 4; ++q)
            #pragma unroll
            for (int r = 0; r < 4; ++r)
                xB[q * 4 + r] = *(const float4*)&xw[r * NU + k0 + 16 + q * 4];

        // ---- compute half k0 from A banks (zero load-use waits inside)
        #pragma unroll
        for (int q = 0; q < 4; ++q)
            #pragma unroll
            for (int kk = 0; kk < 4; ++kk) {
                float2 wv = wA[q * 4 + kk];
                #pragma unroll
                for (int r = 0; r < 4; ++r) {
                    float xv = ((const float*)&xA[q * 4 + r])[kk];
                    acc[r].x = __builtin_fmaf(xv, wv.x, acc[r].x);
                    acc[r].y = __builtin_fmaf(xv, wv.y, acc[r].y);
                }
            }

        // ---- prefetch half (k0+32) into A banks
        if (k0 + 32 < NU) {
            #pragma unroll
            for (int j = 0; j < 16; ++j)
                wA[j] = *(const float2*)(wp + (size_t)(k0 + 32 + j) * NU);
            #pragma unroll
            for (int q = 0; q < 4; ++q)
                #pragma unroll
                for (int r = 0; r < 4; ++r)
                    xA[q * 4 + r] = *(const float4*)&xw[r * NU + k0 + 32 + q * 4];
        }

        // ---- compute half k0+16 from B banks
        #pragma unroll
        for (int q = 0; q < 4; ++q)
            #pragma unroll
            for (int kk = 0; kk < 4; ++kk) {
                float2 wv = wB[q * 4 + kk];
                #pragma unroll
                for (int r = 0; r < 4; ++r) {
                    float xv = ((const float*)&xB[q * 4 + r])[kk];
                    acc[r].x = __builtin_fmaf(xv, wv.x, acc[r].x);
                    acc[r].y = __builtin_fmaf(xv, wv.y, acc[r].y);
                }
            }
    }

    #pragma unroll
    for (int r = 0; r < 4; ++r)
        *(float2*)&ws[(size_t)(m0 + rb + r) * NU + n0 + lane * 2] = acc[r];
}

// ---------------- Phase B: recurrence from t=2 (unchanged, proven) ---------
__global__ __launch_bounds__(BLK) void lif_recurrence(
    const float* __restrict__ x,
    const float* __restrict__ W,
    const float* __restrict__ V1,
    float* __restrict__ out)
{
    const int b    = blockIdx.x;
    const int tid  = threadIdx.x;
    const int lane = tid & 63;
    const int wid  = tid >> 6;

    __shared__ int           s_idx[NU];      // spiking row offsets (k*NU)
    __shared__ unsigned char s_flag[NU];
    __shared__ int           s_wsum[NWAVES];
    __shared__ int           s_cnt;

    const int n0 = tid;
    const int n1 = tid + BLK;

    float* outb = out + (size_t)b * TSTEPS * NU;   // (B, T, N)

    float V0, V1r;
    int   z0, z1;
    {
        float x0 = x[(size_t)b * NU + n0];
        float x1 = x[(size_t)b * NU + n1];
        outb[n0] = x0;
        outb[n1] = x1;
        V0  = V1[(size_t)b * NU + n0];
        V1r = V1[(size_t)b * NU + n1];
        z0 = V0  > 1.0f;
        z1 = V1r > 1.0f;
        float* f1 = outb + NU;
        f1[n0] = z0 ? 1.0f : 0.0f;
        f1[n1] = z1 ? 1.0f : 0.0f;
        s_flag[n0] = (unsigned char)z0;
        s_flag[n1] = (unsigned char)z1;
    }
    __syncthreads();

    for (int t = 2; t < TSTEPS; ++t) {
        int f0 = s_flag[2 * tid];
        int f1 = s_flag[2 * tid + 1];
        int c  = f0 + f1;
        int v  = c;
        #pragma unroll
        for (int d = 1; d < 64; d <<= 1) {
            int o = __shfl_up(v, d);
            if (lane >= d) v += o;
        }
        if (lane == 63) s_wsum[wid] = v;
        __syncthreads();
        int base = 0;
        #pragma unroll
        for (int w = 0; w < NWAVES; ++w) base += (w < wid) ? s_wsum[w] : 0;
        int off = base + v - c;                   // exclusive prefix
        if (f0) s_idx[off++] = (2 * tid) * NU;
        if (f1) s_idx[off]   = (2 * tid + 1) * NU;
        if (tid == BLK - 1) s_cnt = base + v;
        __syncthreads();

        int cnt = s_cnt;
        if (cnt == 0) {
            size_t  elems  = (size_t)(TSTEPS - t) * NU;
            float4* p      = (float4*)(outb + (size_t)t * NU);
            int     chunks = (int)(elems / 4);
            float4  zz; zz.x = zz.y = zz.z = zz.w = 0.0f;
            for (int i = tid; i < chunks; i += BLK) p[i] = zz;
            return;
        }

        float I0 = 0.0f, I1 = 0.0f;
        const float* Wc = W + tid;
        int i = 0;
        for (; i + 4 <= cnt; i += 4) {
            const float* r0 = Wc + s_idx[i];
            const float* r1 = Wc + s_idx[i + 1];
            const float* r2 = Wc + s_idx[i + 2];
            const float* r3 = Wc + s_idx[i + 3];
            float a0 = r0[0], b0 = r0[BLK];
            float a1 = r1[0], b1 = r1[BLK];
            float a2 = r2[0], b2 = r2[BLK];
            float a3 = r3[0], b3 = r3[BLK];
            I0 += a0; I0 += a1; I0 += a2; I0 += a3;   // order preserved
            I1 += b0; I1 += b1; I1 += b2; I1 += b3;
        }
        for (; i < cnt; ++i) {
            const float* r = Wc + s_idx[i];
            I0 += r[0];
            I1 += r[BLK];
        }

        float d0 = 0.90483741803595952f * V0;     // one rounding
        float d1 = 0.90483741803595952f * V1r;
        asm volatile("" : "+v"(d0), "+v"(d1));    // forbid fma-contraction
        float nv0 = (z0 ? 0.0f : d0) + I0;        // one rounding
        float nv1 = (z1 ? 0.0f : d1) + I1;
        V0 = nv0; V1r = nv1;
        z0 = nv0 > 1.0f;
        z1 = nv1 > 1.0f;

        float* po = outb + (size_t)t * NU;
        po[n0] = z0 ? 1.0f : 0.0f;
        po[n1] = z1 ? 1.0f : 0.0f;
        s_flag[n0] = (unsigned char)z0;
        s_flag[n1] = (unsigned char)z1;
        __syncthreads();
    }
}

// ---------------- Fallback: round-4 fused kernel (proven) ------------------
__global__ __launch_bounds__(BLK) void lif_fused(
    const float* __restrict__ x,
    const float* __restrict__ W,
    float* __restrict__ out)
{
    const int b    = blockIdx.x;
    const int tid  = threadIdx.x;
    const int lane = tid & 63;
    const int wid  = tid >> 6;

    __shared__ float         s_x[NU];
    __shared__ int           s_idx[NU];
    __shared__ unsigned char s_flag[NU];
    __shared__ int           s_wsum[NWAVES];
    __shared__ int           s_cnt;

    const int n0 = tid;
    const int n1 = tid + BLK;
    float* outb = out + (size_t)b * TSTEPS * NU;

    {
        float x0 = x[(size_t)b * NU + n0];
        float x1 = x[(size_t)b * NU + n1];
        s_x[n0] = x0; s_x[n1] = x1;
        outb[n0] = x0; outb[n1] = x1;
    }
    __syncthreads();

    float I0 = 0.0f, I1 = 0.0f;
    {
        const float* Wc = W + tid;
        #pragma unroll 8
        for (int k = 0; k < NU; ++k) {
            float xk = s_x[k];
            const float* wr = Wc + (size_t)k * NU;
            I0 = __builtin_fmaf(xk, wr[0],   I0);
            I1 = __builtin_fmaf(xk, wr[BLK], I1);
        }
    }

    float V0 = 0.0f, V1 = 0.0f;
    int   z0 = 0,    z1 = 0;

    for (int t = 1; t < TSTEPS; ++t) {
        if (t >= 2) {
            int f0 = s_flag[2 * tid];
            int f1 = s_flag[2 * tid + 1];
            int c  = f0 + f1;
            int v  = c;
            #pragma unroll
            for (int d = 1; d < 64; d <<= 1) {
                int o = __shfl_up(v, d);
                if (lane >= d) v += o;
            }
            if (lane == 63) s_wsum[wid] = v;
            __syncthreads();
            int base = 0;
            #pragma unroll
            for (int w = 0; w < NWAVES; ++w) base += (w < wid) ? s_wsum[w] : 0;
            int off = base + v - c;
            if (f0) s_idx[off++] = 2 * tid;
            if (f1) s_idx[off]   = 2 * tid + 1;
            if (tid == BLK - 1) s_cnt = base + v;
            __syncthreads();

            int cnt = s_cnt;
            if (cnt == 0) {
                size_t  elems  = (size_t)(TSTEPS - t) * NU;
                float4* p      = (float4*)(outb + (size_t)t * NU);
                int     chunks = (int)(elems / 4);
                float4  zz; zz.x = zz.y = zz.z = zz.w = 0.0f;
                for (int i = tid; i < chunks; i += BLK) p[i] = zz;
                return;
            }

            I0 = 0.0f; I1 = 0.0f;
            const float* Wc = W + tid;
            int i = 0;
            for (; i + 2 <= cnt; i += 2) {
                const float* r0 = Wc + (size_t)s_idx[i]     * NU;
                const float* r1 = Wc + (size_t)s_idx[i + 1] * NU;
                float a0 = r0[0], b0 = r0[BLK];
                float a1 = r1[0], b1 = r1[BLK];
                I0 += a0; I0 += a1;
                I1 += b0; I1 += b1;
            }
            for (; i < cnt; ++i) {
                const float* r = Wc + (size_t)s_idx[i] * NU;
                I0 += r[0];
                I1 += r[BLK];
            }
        }

        float d0 = 0.90483741803595952f * V0;
        float d1 = 0.90483741803595952f * V1;
        asm volatile("" : "+v"(d0), "+v"(d1));
        float nv0 = (z0 ? 0.0f : d0) + I0;
        float nv1 = (z1 ? 0.0f : d1) + I1;
        V0 = nv0; V1 = nv1;
        z0 = nv0 > 1.0f;
        z1 = nv1 > 1.0f;

        float* po = outb + (size_t)t * NU;
        po[n0] = z0 ? 1.0f : 0.0f;
        po[n1] = z1 ? 1.0f : 0.0f;
        s_flag[n0] = (unsigned char)z0;
        s_flag[n1] = (unsigned char)z1;
        __syncthreads();
    }
}

extern "C" void kernel_launch(void* const* d_in, const int* in_sizes, int n_in,
                              void* d_out, int out_size, void* d_ws, size_t ws_size,
                              hipStream_t stream) {
    const float* x = (const float*)d_in[0];   // (256, 2048) fp32
    const float* W = (const float*)d_in[1];   // (2048, 2048) fp32
    if (n_in >= 2 && in_sizes[0] == NU * NU && in_sizes[1] == BATCHSZ * NU) {
        const float* t = x; x = W; W = t;     // defensive input-order swap
    }
    float* out = (float*)d_out;               // (B, T, N) fp32

    const size_t need = (size_t)BATCHSZ * NU * sizeof(float);   // 2 MB
    if (ws_size >= need) {
        float* V1 = (float*)d_ws;
        hipLaunchKernelGGL(lif_dense_v1,
                           dim3(512), dim3(128), 0, stream,
                           x, W, V1);
        hipLaunchKernelGGL(lif_recurrence,
                           dim3(BATCHSZ), dim3(BLK), 0, stream,
                           x, W, V1, out);
    } else {
        hipLaunchKernelGGL(lif_fused, dim3(BATCHSZ), dim3(BLK), 0, stream,
                           x, W, out);
    }
}